// Round 14
// baseline (489.063 us; speedup 1.0000x reference)
//
#include <hip/hip_runtime.h>
#include <hip/hip_bf16.h>
#include <math.h>

#define N 8192
#define FIN 256
#define D 64
#define ALPHA 0.2f
#define SROW 1040          // staged mask row: 1024 B + 16 pad (bank spread)
#define WBUF (16 * SROW)   // 16.25 KB per wave
#define CS 2048            // columns per wave (4 waves cover N)
#define NBLK 512           // grid size; 2 blocks/CU -> all co-resident

typedef __attribute__((ext_vector_type(8))) short bf16x8;
typedef __attribute__((ext_vector_type(4))) float f32x4;

// One fused kernel, 512 blocks x 256 threads, exactly 2 blocks/CU (LDS 66.8 KB,
// VGPR capped 128 by launch_bounds) -> all blocks co-resident -> arrive/spin
// device barrier is safe.
// Phase H: block b computes h rows 16b..16b+15 (fp32), e1/e2, hF fragments.
// Barrier: agent-scope release -> atomic arrive -> issue ss0 mask DMA -> spin.
// Phase A: R13 attn body unchanged (nt global_load_lds mask staging, hF/e2
// register prefetch, LDS cross-wave combine, direct out write).
__global__ __launch_bounds__(256, 4) void k_fused(
    const float* __restrict__ x, const int* __restrict__ mask,
    const float* __restrict__ trans, const float* __restrict__ attn,
    __hip_bfloat16* __restrict__ hF, float* __restrict__ e1,
    float* __restrict__ e2, float* __restrict__ out,
    unsigned* __restrict__ flag)
{
    __shared__ __align__(16) char smem[4 * WBUF];   // 65 KB: mask bufs / xs+hl
    __shared__ float lw[4][16];
    const int t = threadIdx.x;
    const int b = blockIdx.x;
    const int lane = t & 63, wave = t >> 6;

    // ================= Phase H: 16 rows of h = x@trans, e1/e2, hF =============
    {
        float* xs = (float*)smem;                        // [16][FIN] = 16 KB
        __hip_bfloat16* hl = (__hip_bfloat16*)(smem + 16 * FIN * 4);  // [16][64]
        const int r0 = b * 16;

        #pragma unroll
        for (int v = 0; v < 4; ++v) {
            int idx = t + 256 * v;                       // 1024 float4 slots
            ((float4*)xs)[idx] = ((const float4*)(x + (size_t)r0 * FIN))[idx];
        }
        __syncthreads();

        // wave w: rows r0+4w .. r0+4w+3, lane = output col d
        float acc[4] = {0.f, 0.f, 0.f, 0.f};
        const float* xr = xs + (4 * wave) * FIN;
        #pragma unroll 4
        for (int k = 0; k < FIN; ++k) {
            const float tv = trans[k * D + lane];
            acc[0] = fmaf(xr[k], tv, acc[0]);
            acc[1] = fmaf(xr[k + FIN], tv, acc[1]);
            acc[2] = fmaf(xr[k + 2 * FIN], tv, acc[2]);
            acc[3] = fmaf(xr[k + 3 * FIN], tv, acc[3]);
        }

        const float a1 = attn[lane], a2 = attn[D + lane];
        #pragma unroll
        for (int j = 0; j < 4; ++j) {
            float p1 = acc[j] * a1, p2 = acc[j] * a2;
            #pragma unroll
            for (int mm = 1; mm <= 32; mm <<= 1) {
                p1 += __shfl_xor(p1, mm);
                p2 += __shfl_xor(p2, mm);
            }
            if (lane == 0) { e1[r0 + 4 * wave + j] = p1; e2[r0 + 4 * wave + j] = p2; }
            hl[(4 * wave + j) * D + lane] = __float2bfloat16(acc[j]);
        }
        __syncthreads();
        if (t < 128) {
            const int half = t >> 6, tt = t & 63;
            const int q = tt >> 4, m = tt & 15;
            const int rg0 = r0 + 8 * half;               // 8-row fragment group
            const int cb = rg0 >> 5, jgrp = (rg0 >> 3) & 3;
            union { bf16x8 v; __hip_bfloat16 h[8]; } o;
            #pragma unroll
            for (int r = 0; r < 8; ++r) o.h[r] = hl[(8 * half + r) * D + q * 16 + m];
            *(bf16x8*)(hF + (((size_t)cb * 4 + q) * 64 + jgrp * 16 + m) * 8) = o.v;
        }
        __syncthreads();   // phase-H LDS use done; smem free for mask staging
    }

    // ================= Device barrier (arrive -> DMA ss0 -> spin) =============
    const int i0 = b * 16;
    const int c0 = wave * CS;
    char* sw = smem + wave * WBUF;

    __threadfence();   // release hF/e1/e2 to device scope (cross-XCD)
    if (t == 0)
        __hip_atomic_fetch_add(flag, 1u, __ATOMIC_ACQ_REL, __HIP_MEMORY_SCOPE_AGENT);

    // issue super-step-0 mask DMA now; it overlaps the spin below
    #pragma unroll
    for (int r = 0; r < 16; ++r) {
        const int* g = mask + (size_t)(i0 + r) * N + c0 + lane * 4;
        char* l = sw + r * SROW + lane * 16;
        __builtin_amdgcn_global_load_lds(
            (const __attribute__((address_space(1))) void*)g,
            (__attribute__((address_space(3))) void*)l, 16, 0, 2 /* nt */);
    }

    if (t == 0) {
        while (__hip_atomic_load(flag, __ATOMIC_ACQUIRE, __HIP_MEMORY_SCOPE_AGENT)
               < (unsigned)NBLK) { }
    }
    __syncthreads();
    __threadfence();   // acquire: discard stale copies of other blocks' hF/e1/e2

    // ================= Phase A: masked softmax-attention (R13 body) ===========
    const int m = lane & 15, quad = lane >> 4;
    const int row = i0 + m;
    const float er = e1[row];
    const char* swm = sw + m * SROW;
    const __hip_bfloat16* hfp = hF + (((size_t)(c0 >> 5)) * 4 * 64 + lane) * 8;

    f32x4 acc0 = {0.f, 0.f, 0.f, 0.f};
    f32x4 acc1 = {0.f, 0.f, 0.f, 0.f};
    f32x4 acc2 = {0.f, 0.f, 0.f, 0.f};
    f32x4 acc3 = {0.f, 0.f, 0.f, 0.f};
    float lsum = 0.f;

    const int nss = CS >> 8;   // 8 super-steps of 256 cols

    for (int ss = 0; ss < nss; ++ss) {
        const int cb0 = c0 + ss * 256;
        if (ss > 0) {   // ss0 DMA already issued above
            #pragma unroll
            for (int r = 0; r < 16; ++r) {
                const int* g = mask + (size_t)(i0 + r) * N + cb0 + lane * 4;
                char* l = sw + r * SROW + lane * 16;
                __builtin_amdgcn_global_load_lds(
                    (const __attribute__((address_space(1))) void*)g,
                    (__attribute__((address_space(3))) void*)l, 16, 0, 2 /* nt */);
            }
        }
        __builtin_amdgcn_s_waitcnt(0x0F70);   // vmcnt(0): LDS tile ready

        const int itg0 = ss * 8;
        bf16x8 pb0, pb1, pb2, pb3; float4 pea, peb;
        {
            const size_t ito = (size_t)itg0 * 2048;
            pb0 = *(const bf16x8*)(hfp + ito);
            pb1 = *(const bf16x8*)(hfp + ito + 512);
            pb2 = *(const bf16x8*)(hfp + ito + 1024);
            pb3 = *(const bf16x8*)(hfp + ito + 1536);
            const int jb = cb0 + quad * 8;
            pea = *(const float4*)(e2 + jb);
            peb = *(const float4*)(e2 + jb + 4);
        }
        #pragma unroll
        for (int p = 0; p < 8; ++p) {
            const bf16x8 b0 = pb0, b1 = pb1, b2 = pb2, b3 = pb3;
            const float4 ea = pea, eb = peb;
            if (p < 7) {
                const size_t ito = (size_t)(itg0 + p + 1) * 2048;
                pb0 = *(const bf16x8*)(hfp + ito);
                pb1 = *(const bf16x8*)(hfp + ito + 512);
                pb2 = *(const bf16x8*)(hfp + ito + 1024);
                pb3 = *(const bf16x8*)(hfp + ito + 1536);
                const int jb = cb0 + (p + 1) * 32 + quad * 8;
                pea = *(const float4*)(e2 + jb);
                peb = *(const float4*)(e2 + jb + 4);
            }
            const int4 m0 = *(const int4*)(swm + p * 128 + quad * 32);
            const int4 m1 = *(const int4*)(swm + p * 128 + quad * 32 + 16);

            float s0 = er + ea.x; s0 = s0 > 0.f ? s0 : ALPHA * s0;
            float s1 = er + ea.y; s1 = s1 > 0.f ? s1 : ALPHA * s1;
            float s2 = er + ea.z; s2 = s2 > 0.f ? s2 : ALPHA * s2;
            float s3 = er + ea.w; s3 = s3 > 0.f ? s3 : ALPHA * s3;
            float s4 = er + eb.x; s4 = s4 > 0.f ? s4 : ALPHA * s4;
            float s5 = er + eb.y; s5 = s5 > 0.f ? s5 : ALPHA * s5;
            float s6 = er + eb.z; s6 = s6 > 0.f ? s6 : ALPHA * s6;
            float s7 = er + eb.w; s7 = s7 > 0.f ? s7 : ALPHA * s7;
            const float p0 = m0.x ? __expf(s0) : 0.f;
            const float p1 = m0.y ? __expf(s1) : 0.f;
            const float p2 = m0.z ? __expf(s2) : 0.f;
            const float p3 = m0.w ? __expf(s3) : 0.f;
            const float p4 = m1.x ? __expf(s4) : 0.f;
            const float p5 = m1.y ? __expf(s5) : 0.f;
            const float p6 = m1.z ? __expf(s6) : 0.f;
            const float p7 = m1.w ? __expf(s7) : 0.f;

            union { bf16x8 v; __hip_bfloat162 h2[4]; } af;
            af.h2[0] = __float22bfloat162_rn(make_float2(p0, p1));
            af.h2[1] = __float22bfloat162_rn(make_float2(p2, p3));
            af.h2[2] = __float22bfloat162_rn(make_float2(p4, p5));
            af.h2[3] = __float22bfloat162_rn(make_float2(p6, p7));

            lsum += ((p0 + p1) + (p2 + p3)) + ((p4 + p5) + (p6 + p7));

            acc0 = __builtin_amdgcn_mfma_f32_16x16x32_bf16(af.v, b0, acc0, 0, 0, 0);
            acc1 = __builtin_amdgcn_mfma_f32_16x16x32_bf16(af.v, b1, acc1, 0, 0, 0);
            acc2 = __builtin_amdgcn_mfma_f32_16x16x32_bf16(af.v, b2, acc2, 0, 0, 0);
            acc3 = __builtin_amdgcn_mfma_f32_16x16x32_bf16(af.v, b3, acc3, 0, 0, 0);
        }
    }

    // per-wave row sums: row m's cols live in lanes m, m+16, m+32, m+48
    lsum += __shfl_xor(lsum, 16);
    lsum += __shfl_xor(lsum, 32);
    if (quad == 0) lw[wave][m] = lsum;

    // cross-wave combine in LDS (alias over dead mask buffers)
    __syncthreads();
    float* cw = (float*)smem;   // [4][16][64] fp32
    #pragma unroll
    for (int reg = 0; reg < 4; ++reg) {
        float* rbase = cw + (wave * 16 + quad * 4 + reg) * 64;
        rbase[m     ] = acc0[reg];
        rbase[m + 16] = acc1[reg];
        rbase[m + 32] = acc2[reg];
        rbase[m + 48] = acc3[reg];
    }
    __syncthreads();
    #pragma unroll
    for (int rr = 0; rr < 4; ++rr) {
        const int idx = rr * 256 + t;
        const int r = idx >> 6, c = idx & 63;
        float s = ((cw[(0 * 16 + r) * 64 + c] + cw[(1 * 16 + r) * 64 + c])
                +   cw[(2 * 16 + r) * 64 + c]) + cw[(3 * 16 + r) * 64 + c];
        float l = ((lw[0][r] + lw[1][r]) + lw[2][r]) + lw[3][r];
        out[(size_t)(i0 + r) * D + c] = s / l;
    }
}

extern "C" void kernel_launch(void* const* d_in, const int* in_sizes, int n_in,
                              void* d_out, int out_size, void* d_ws, size_t ws_size,
                              hipStream_t stream) {
    const float* x     = (const float*)d_in[0];
    const int*   mask  = (const int*)d_in[1];
    const float* trans = (const float*)d_in[2];
    const float* attn  = (const float*)d_in[3];
    float* out = (float*)d_out;

    char* ws = (char*)d_ws;
    __hip_bfloat16* hF = (__hip_bfloat16*)ws;                 // 1 MB
    char* p = ws + (size_t)D * N * sizeof(__hip_bfloat16);
    float* e1 = (float*)p;            p += (size_t)N * sizeof(float);
    float* e2 = (float*)p;            p += (size_t)N * sizeof(float);
    unsigned* flag = (unsigned*)p;

    hipMemsetAsync(flag, 0, sizeof(unsigned), stream);   // ws is 0xAA-poisoned
    k_fused<<<NBLK, 256, 0, stream>>>(x, mask, trans, attn, hF, e1, e2, out, flag);
}

// Round 15
// 383.680 us; speedup vs baseline: 1.2747x; 1.2747x over previous
//
#include <hip/hip_runtime.h>
#include <hip/hip_bf16.h>
#include <math.h>

#define N 8192
#define FIN 256
#define D 64
#define ALPHA 0.2f
#define SROW 528           // staged mask row: 512 B + 16 pad
#define WBUF (16 * SROW)   // 8.25 KB per wave -> 33 KB/block -> 4 blocks/CU
#define NSPLIT 2
#define CS 1024            // columns per wave (4 waves x 1024 = 4096-col slab)

typedef __attribute__((ext_vector_type(8))) short bf16x8;
typedef __attribute__((ext_vector_type(4))) float f32x4;

// ---------------- Kernel 1: h = x@trans (fp32), e1/e2 (fp32), hF fragment-order
__global__ __launch_bounds__(256) void k_h_e(
    const float* __restrict__ x, const float* __restrict__ trans,
    const float* __restrict__ attn,
    __hip_bfloat16* __restrict__ hF, float* __restrict__ e1, float* __restrict__ e2)
{
    __shared__ float xs[8 * FIN];
    __shared__ __hip_bfloat16 hl[8 * D];
    const int t = threadIdx.x;
    const int r0 = blockIdx.x * 8;

    #pragma unroll
    for (int v = 0; v < 2; ++v) {
        int idx = t + 256 * v;
        ((float4*)xs)[idx] = ((const float4*)(x + (size_t)r0 * FIN))[idx];
    }
    __syncthreads();

    const int lane = t & 63, w = t >> 6;
    const float* xa = xs + (2 * w) * FIN;
    const float* xb = xs + (2 * w + 1) * FIN;
    float acca = 0.f, accb = 0.f;
    #pragma unroll 8
    for (int k = 0; k < FIN; ++k) {
        const float tv = trans[k * D + lane];
        acca = fmaf(xa[k], tv, acca);
        accb = fmaf(xb[k], tv, accb);
    }
    const int ra = r0 + 2 * w, rb = ra + 1;

    const float a1 = attn[lane], a2 = attn[D + lane];
    float p1a = acca * a1, p2a = acca * a2;
    float p1b = accb * a1, p2b = accb * a2;
    #pragma unroll
    for (int mm = 1; mm <= 32; mm <<= 1) {
        p1a += __shfl_xor(p1a, mm);
        p2a += __shfl_xor(p2a, mm);
        p1b += __shfl_xor(p1b, mm);
        p2b += __shfl_xor(p2b, mm);
    }
    if (lane == 0) { e1[ra] = p1a; e2[ra] = p2a; e1[rb] = p1b; e2[rb] = p2b; }

    hl[(2 * w) * D + lane]     = __float2bfloat16(acca);
    hl[(2 * w + 1) * D + lane] = __float2bfloat16(accb);
    __syncthreads();
    if (t < D) {
        const int q = t >> 4, m = t & 15;
        const int cb = r0 >> 5, jgrp = (r0 >> 3) & 3;
        union { bf16x8 v; __hip_bfloat16 h[8]; } o;
        #pragma unroll
        for (int r = 0; r < 8; ++r) o.h[r] = hl[r * D + q * 16 + m];
        *(bf16x8*)(hF + (((size_t)cb * 4 + q) * 64 + jgrp * 16 + m) * 8) = o.v;
    }
}

// ---------------- Kernel 2: masked softmax-attention, 128-col super-steps ------
// DISCRIMINATOR build: SS halved to 128 cols -> 33-KB blocks -> 4 blocks/CU,
// 16 waves/CU (2x wave-level parallelism on the DMA convoy). nsplit=2 restores
// a 1024-block grid. Body logic otherwise identical to R13.
__global__ __launch_bounds__(256, 4) void k_attn(
    const int* __restrict__ mask, const __hip_bfloat16* __restrict__ hF,
    const float* __restrict__ e1, const float* __restrict__ e2,
    float* __restrict__ acc_part, float* __restrict__ l_part)
{
    __shared__ __align__(16) char smem[4 * WBUF];   // 33 KB
    __shared__ float lw[4][16];
    const int t = threadIdx.x;
    const int lane = t & 63, wave = t >> 6;
    const int sp = blockIdx.x;                       // split 0/1
    const int i0 = blockIdx.y * 16;
    const int c0 = sp * (NSPLIT == 2 ? 4096 : 0) + wave * CS;
    const int m = lane & 15, quad = lane >> 4;
    const int row = i0 + m;
    const float er = e1[row];

    char* sw = smem + wave * WBUF;
    const char* swm = sw + m * SROW;
    const __hip_bfloat16* hfp = hF + (((size_t)(c0 >> 5)) * 4 * 64 + lane) * 8;

    f32x4 acc0 = {0.f, 0.f, 0.f, 0.f};
    f32x4 acc1 = {0.f, 0.f, 0.f, 0.f};
    f32x4 acc2 = {0.f, 0.f, 0.f, 0.f};
    f32x4 acc3 = {0.f, 0.f, 0.f, 0.f};
    float lsum = 0.f;

    const int nss = CS >> 7;   // 8 super-steps of 4 iterations (128 cols) each

    for (int ss = 0; ss < nss; ++ss) {
        const int cb0 = c0 + ss * 128;
        // ---- stage: 16 rows x 512 B contiguous (2 x 4-B DMA per row)
        #pragma unroll
        for (int r = 0; r < 16; ++r) {
            const int* g = mask + (size_t)(i0 + r) * N + cb0 + lane;
            char* l = sw + r * SROW + lane * 4;
            __builtin_amdgcn_global_load_lds(
                (const __attribute__((address_space(1))) void*)g,
                (__attribute__((address_space(3))) void*)l, 4, 0, 2 /* nt */);
            __builtin_amdgcn_global_load_lds(
                (const __attribute__((address_space(1))) void*)(g + 64),
                (__attribute__((address_space(3))) void*)(l + 256), 4, 0, 2);
        }
        __builtin_amdgcn_s_waitcnt(0x0F70);   // vmcnt(0): LDS tile ready

        const int itg0 = ss * 4;
        // prefetch iter 0's hF/e2
        bf16x8 pb0, pb1, pb2, pb3; float4 pea, peb;
        {
            const size_t ito = (size_t)itg0 * 2048;
            pb0 = *(const bf16x8*)(hfp + ito);
            pb1 = *(const bf16x8*)(hfp + ito + 512);
            pb2 = *(const bf16x8*)(hfp + ito + 1024);
            pb3 = *(const bf16x8*)(hfp + ito + 1536);
            const int jb = cb0 + quad * 8;
            pea = *(const float4*)(e2 + jb);
            peb = *(const float4*)(e2 + jb + 4);
        }
        #pragma unroll
        for (int p = 0; p < 4; ++p) {
            const bf16x8 b0 = pb0, b1 = pb1, b2 = pb2, b3 = pb3;
            const float4 ea = pea, eb = peb;
            if (p < 3) {   // issue iter p+1's loads BEFORE consuming iter p
                const size_t ito = (size_t)(itg0 + p + 1) * 2048;
                pb0 = *(const bf16x8*)(hfp + ito);
                pb1 = *(const bf16x8*)(hfp + ito + 512);
                pb2 = *(const bf16x8*)(hfp + ito + 1024);
                pb3 = *(const bf16x8*)(hfp + ito + 1536);
                const int jb = cb0 + (p + 1) * 32 + quad * 8;
                pea = *(const float4*)(e2 + jb);
                peb = *(const float4*)(e2 + jb + 4);
            }
            const int4 m0 = *(const int4*)(swm + p * 128 + quad * 32);
            const int4 m1 = *(const int4*)(swm + p * 128 + quad * 32 + 16);

            float s0 = er + ea.x; s0 = s0 > 0.f ? s0 : ALPHA * s0;
            float s1 = er + ea.y; s1 = s1 > 0.f ? s1 : ALPHA * s1;
            float s2 = er + ea.z; s2 = s2 > 0.f ? s2 : ALPHA * s2;
            float s3 = er + ea.w; s3 = s3 > 0.f ? s3 : ALPHA * s3;
            float s4 = er + eb.x; s4 = s4 > 0.f ? s4 : ALPHA * s4;
            float s5 = er + eb.y; s5 = s5 > 0.f ? s5 : ALPHA * s5;
            float s6 = er + eb.z; s6 = s6 > 0.f ? s6 : ALPHA * s6;
            float s7 = er + eb.w; s7 = s7 > 0.f ? s7 : ALPHA * s7;
            const float p0 = m0.x ? __expf(s0) : 0.f;
            const float p1 = m0.y ? __expf(s1) : 0.f;
            const float p2 = m0.z ? __expf(s2) : 0.f;
            const float p3 = m0.w ? __expf(s3) : 0.f;
            const float p4 = m1.x ? __expf(s4) : 0.f;
            const float p5 = m1.y ? __expf(s5) : 0.f;
            const float p6 = m1.z ? __expf(s6) : 0.f;
            const float p7 = m1.w ? __expf(s7) : 0.f;

            union { bf16x8 v; __hip_bfloat162 h2[4]; } af;
            af.h2[0] = __float22bfloat162_rn(make_float2(p0, p1));
            af.h2[1] = __float22bfloat162_rn(make_float2(p2, p3));
            af.h2[2] = __float22bfloat162_rn(make_float2(p4, p5));
            af.h2[3] = __float22bfloat162_rn(make_float2(p6, p7));

            lsum += ((p0 + p1) + (p2 + p3)) + ((p4 + p5) + (p6 + p7));

            acc0 = __builtin_amdgcn_mfma_f32_16x16x32_bf16(af.v, b0, acc0, 0, 0, 0);
            acc1 = __builtin_amdgcn_mfma_f32_16x16x32_bf16(af.v, b1, acc1, 0, 0, 0);
            acc2 = __builtin_amdgcn_mfma_f32_16x16x32_bf16(af.v, b2, acc2, 0, 0, 0);
            acc3 = __builtin_amdgcn_mfma_f32_16x16x32_bf16(af.v, b3, acc3, 0, 0, 0);
        }
    }

    // per-wave row sums: row m's cols live in lanes m, m+16, m+32, m+48
    lsum += __shfl_xor(lsum, 16);
    lsum += __shfl_xor(lsum, 32);
    if (quad == 0) lw[wave][m] = lsum;

    // cross-wave combine in LDS (alias over dead mask buffers), then acc_part
    __syncthreads();
    float* cw = (float*)smem;   // [4][16][64] fp32 = 16 KB
    #pragma unroll
    for (int reg = 0; reg < 4; ++reg) {
        float* rbase = cw + (wave * 16 + quad * 4 + reg) * 64;
        rbase[m     ] = acc0[reg];
        rbase[m + 16] = acc1[reg];
        rbase[m + 32] = acc2[reg];
        rbase[m + 48] = acc3[reg];
    }
    __syncthreads();
    #pragma unroll
    for (int rr = 0; rr < 4; ++rr) {
        const int idx = rr * 256 + t;
        const int r = idx >> 6, c = idx & 63;
        float s = ((cw[(0 * 16 + r) * 64 + c] + cw[(1 * 16 + r) * 64 + c])
                +   cw[(2 * 16 + r) * 64 + c]) + cw[(3 * 16 + r) * 64 + c];
        acc_part[((size_t)sp * N + i0 + r) * D + c] = s;
        if (idx < 64 && (idx & 3) == 0) { /* no-op filler */ }
    }
    if (t < 16)
        l_part[(size_t)sp * N + i0 + t]
            = ((lw[0][t] + lw[1][t]) + lw[2][t]) + lw[3][t];
}

// ---------------- Kernel 3: combine 2 splits, divide by l ----------------------
__global__ __launch_bounds__(256) void k_reduce(
    const float* __restrict__ acc_part, const float* __restrict__ l_part,
    float* __restrict__ out)
{
    const int idx = blockIdx.x * 256 + threadIdx.x;
    const int row = idx >> 6;
    float sum = acc_part[idx] + acc_part[(size_t)N * D + idx];
    float l = l_part[row] + l_part[(size_t)N + row];
    out[idx] = sum / l;
}

extern "C" void kernel_launch(void* const* d_in, const int* in_sizes, int n_in,
                              void* d_out, int out_size, void* d_ws, size_t ws_size,
                              hipStream_t stream) {
    const float* x     = (const float*)d_in[0];
    const int*   mask  = (const int*)d_in[1];
    const float* trans = (const float*)d_in[2];
    const float* attn  = (const float*)d_in[3];
    float* out = (float*)d_out;

    char* ws = (char*)d_ws;
    __hip_bfloat16* hF = (__hip_bfloat16*)ws;                 // 1 MB
    char* p = ws + (size_t)D * N * sizeof(__hip_bfloat16);
    float* e1 = (float*)p;            p += (size_t)N * sizeof(float);
    float* e2 = (float*)p;            p += (size_t)N * sizeof(float);
    float* l_part = (float*)p;        p += (size_t)NSPLIT * N * sizeof(float);
    float* acc_part = (float*)p;      // NSPLIT * N * D floats = 4 MB

    k_h_e<<<N / 8, 256, 0, stream>>>(x, trans, attn, hF, e1, e2);
    dim3 g2(NSPLIT, N / 16);
    k_attn<<<g2, 256, 0, stream>>>(mask, hF, e1, e2, acc_part, l_part);
    k_reduce<<<(N * D) / 256, 256, 0, stream>>>(acc_part, l_part, out);
}